// Round 13
// baseline (396.489 us; speedup 1.0000x reference)
//
#include <hip/hip_runtime.h>

#define NN 2000
#define BB 8
#define P  2048   // padded dim for all MFMA operands
#define NIT 32    // K iterations of 64 for k_gd

typedef __attribute__((ext_vector_type(8))) short bf16x8;
typedef __attribute__((ext_vector_type(4))) float f32x4;

__device__ __forceinline__ float sigf(float x) { return 1.0f / (1.0f + expf(-x)); }

__device__ __forceinline__ short f2bf(float x) {
    union { float f; unsigned u; } v; v.f = x;
    unsigned r = v.u + 0x7fffu + ((v.u >> 16) & 1u);   // round-nearest-even
    return (short)(r >> 16);
}
__device__ __forceinline__ float bf2f(short h) {
    union { unsigned u; float f; } v; v.u = ((unsigned)(unsigned short)h) << 16; return v.f;
}

__device__ __forceinline__ void gl2lds16(const short* g, short* l) {
    __builtin_amdgcn_global_load_lds(
        (const __attribute__((address_space(1))) void*)g,
        (__attribute__((address_space(3))) void*)l, 16, 0, 0);
}

// ---------------------------------------------------------------------------
// k_cvt: merged weight conversion + dynamic-adjacency build.
// sel 0-2: W2/W3/adj fp32 [2000][2000] -> bf16 [P][P] zero-padded.
// sel 3  : d1bf[b][i][j] for ALL 8 batches from ONE windd-row read, using
//          cos(|w-wn|) = cos(w)cos(wn)+sin(w)sin(wn)  (identity; the >360
//          clamp is unreachable for w,wn in [0,360]). Trig count /4.
// ---------------------------------------------------------------------------
__global__ __launch_bounds__(256) void k_cvt(
    const float* __restrict__ W2, const float* __restrict__ W3,
    const float* __restrict__ adj, const float* __restrict__ windd,
    const float* __restrict__ inputs,
    short* __restrict__ W2bf, short* __restrict__ W3bf,
    short* __restrict__ adjbf, short* __restrict__ d1bf)
{
    const int i = blockIdx.x, sel = blockIdx.y, t = threadIdx.x;
    const bool live = (i < NN) && (t < 250);
    if (sel < 3) {
        const float* s = (sel == 0) ? W2 : (sel == 1) ? W3 : adj;
        short* d = ((sel == 0) ? W2bf : (sel == 1) ? W3bf : adjbf) + ((size_t)i) * P + t * 8;
        bf16x8 v;
#pragma unroll
        for (int e = 0; e < 8; ++e) v[e] = 0;
        if (live) {
            const float* p = s + (size_t)i * NN + t * 8;
            float4 x0 = *(const float4*)p;
            float4 x1 = *(const float4*)(p + 4);
            float a[8] = {x0.x,x0.y,x0.z,x0.w,x1.x,x1.y,x1.z,x1.w};
#pragma unroll
            for (int e = 0; e < 8; ++e) v[e] = f2bf(a[e]);
        }
        *(bf16x8*)d = v;
    } else {
        const float DEG = 0.01745329251994329577f;
        float cw[8], sw[8];
        if (live) {
            const float* p = windd + (size_t)i * NN + t * 8;
            float4 x0 = *(const float4*)p;
            float4 x1 = *(const float4*)(p + 4);
            float a[8] = {x0.x,x0.y,x0.z,x0.w,x1.x,x1.y,x1.z,x1.w};
#pragma unroll
            for (int e = 0; e < 8; ++e) {
                float r = a[e] * DEG;
                cw[e] = __cosf(r);
                sw[e] = __sinf(r);
            }
        }
        __shared__ float cwn[8], swn[8];
        if (t < 8 && i < NN) {
            float wn = inputs[(size_t)t * 3 * NN + 2 * NN + i] * (360.0f * DEG);
            cwn[t] = __cosf(wn);
            swn[t] = __sinf(wn);
        }
        __syncthreads();
#pragma unroll
        for (int b = 0; b < BB; ++b) {
            bf16x8 v;
#pragma unroll
            for (int e = 0; e < 8; ++e) v[e] = 0;
            if (live) {
                const float cb_ = cwn[b], sb_ = swn[b];
#pragma unroll
                for (int e = 0; e < 8; ++e)
                    v[e] = f2bf(fmaxf(fmaf(cw[e], cb_, sw[e] * sb_), 0.0f));
            }
            *(bf16x8*)(d1bf + ((size_t)b * P + i) * P + t * 8) = v;
        }
    }
}

// ---------------------------------------------------------------------------
// k_gd: wind GEMM (FROZEN R11 structure). 256x256 tile, 8 waves (2M x 4N),
// BK=64, TWO LDS slots, ONE barrier + ONE vmcnt(0) per K-iteration, all 8
// staging loads at iteration top. 128B LDS rows, conflict-free XOR swizzle.
// Epilogue: m_bf + deterministic per-block fp32 row-sum partials (rowpart).
// m_bf[b] = bf16(relu(d1[b]@W2^T + b2 + adjW3) + I), [P][P] zero-padded.
// ---------------------------------------------------------------------------
__global__ __launch_bounds__(512, 2) void k_gd(
    const short* __restrict__ d1bf, const short* __restrict__ W2bf,
    const float* __restrict__ b2, const short* __restrict__ adjw,
    short* __restrict__ m_bf, float* __restrict__ rowpart)
{
    __shared__ char smem[131072];   // A slots: [2][256][128B] at 0; B slots at +65536
    const int t = threadIdx.x;
    const int w = t >> 6, lane = t & 63;
    const int wm = w >> 2, wn = w & 3;
    const int lr = lane & 15, lq = lane >> 4;
    const int tile = blockIdx.x;               // 0..63
    const int b = blockIdx.y;
    const int i0 = (tile & 7) * 256;           // same-XCD blocks share A-panel
    const int j0 = (tile >> 3) * 256;
    const short* A  = d1bf + (size_t)b * P * P;
    const short* Bm = W2bf;

    // staging: chunk c -> row r = c>>3, pos p = c&7, source k-granule g = p^(r&7)
    const short* srcA[4];
    const short* srcB[4];
#pragma unroll
    for (int q = 0; q < 4; ++q) {
        const int c = q * 512 + t;
        const int r = c >> 3;
        const int g = (c & 7) ^ (r & 7);
        srcA[q] = A  + (size_t)(i0 + r) * P + g * 8;
        srcB[q] = Bm + (size_t)(j0 + r) * P + g * 8;
    }

#define STAGE_ALL(slot, ktI) do {                                                      \
        gl2lds16(srcA[0] + (ktI) * 64, (short*)(smem + (slot) * 32768 + (w * 64) * 16));          \
        gl2lds16(srcA[1] + (ktI) * 64, (short*)(smem + (slot) * 32768 + (512 + w * 64) * 16));    \
        gl2lds16(srcA[2] + (ktI) * 64, (short*)(smem + (slot) * 32768 + (1024 + w * 64) * 16));   \
        gl2lds16(srcA[3] + (ktI) * 64, (short*)(smem + (slot) * 32768 + (1536 + w * 64) * 16));   \
        gl2lds16(srcB[0] + (ktI) * 64, (short*)(smem + 65536 + (slot) * 32768 + (w * 64) * 16));          \
        gl2lds16(srcB[1] + (ktI) * 64, (short*)(smem + 65536 + (slot) * 32768 + (512 + w * 64) * 16));    \
        gl2lds16(srcB[2] + (ktI) * 64, (short*)(smem + 65536 + (slot) * 32768 + (1024 + w * 64) * 16));   \
        gl2lds16(srcB[3] + (ktI) * 64, (short*)(smem + 65536 + (slot) * 32768 + (1536 + w * 64) * 16)); } while (0)

    // fragment read offsets: row*128 + ((ks*4+lq) ^ (lr&7))*16
    const int fx0 = (lq << 4) ^ ((lr & 7) << 4);          // ks=0
    const int fx1 = ((4 + lq) << 4) ^ ((lr & 7) << 4);    // ks=1
    const int arowB = (wm * 128 + lr) * 128;              // + m*2048
    const int browB = (wn * 64 + lr) * 128;               // + n*2048

    f32x4 acc[8][4];
#pragma unroll
    for (int m = 0; m < 8; ++m)
#pragma unroll
        for (int n = 0; n < 4; ++n) acc[m][n] = (f32x4){0.f, 0.f, 0.f, 0.f};
    bf16x8 aF[4][2], bF[4][2];

    // prologue: stage kt=0 into slot 0, full drain
    STAGE_ALL(0, 0);
    asm volatile("s_waitcnt vmcnt(0)" ::: "memory");
    __builtin_amdgcn_s_barrier();
    asm volatile("" ::: "memory");

#define MFMA_(a_, b_, m, n) acc[m][n] = __builtin_amdgcn_mfma_f32_16x16x32_bf16(a_, b_, acc[m][n], 0, 0, 0)

    for (int kt = 0; kt < NIT; ++kt) {
        char* curA = smem + (kt & 1) * 32768;
        char* curB = smem + 65536 + (kt & 1) * 32768;
        const int stgSlot = (kt + 1) & 1;
        const int stgKt = (kt + 1 < NIT) ? (kt + 1) : (NIT - 1);  // clamped: never read

        // ---- issue ALL next-slot staging loads first ----
        STAGE_ALL(stgSlot, stgKt);

        // ---- phase A: read A m0-3 + B n0-3; 32 MFMA ----
#pragma unroll
        for (int m = 0; m < 4; ++m) {
            aF[m][0] = *(const bf16x8*)(curA + arowB + m * 2048 + fx0);
            aF[m][1] = *(const bf16x8*)(curA + arowB + m * 2048 + fx1);
        }
#pragma unroll
        for (int n = 0; n < 4; ++n) {
            bF[n][0] = *(const bf16x8*)(curB + browB + n * 2048 + fx0);
            bF[n][1] = *(const bf16x8*)(curB + browB + n * 2048 + fx1);
        }
        asm volatile("s_waitcnt lgkmcnt(0)" ::: "memory");
        __builtin_amdgcn_sched_barrier(0);
        __builtin_amdgcn_s_setprio(1);
#pragma unroll
        for (int m = 0; m < 4; ++m)
#pragma unroll
            for (int n = 0; n < 4; ++n) {
                MFMA_(aF[m][0], bF[n][0], m, n);
                MFMA_(aF[m][1], bF[n][1], m, n);
            }
        __builtin_amdgcn_s_setprio(0);

        // ---- phase B: read A m4-7; 32 MFMA ----
#pragma unroll
        for (int m = 0; m < 4; ++m) {
            aF[m][0] = *(const bf16x8*)(curA + arowB + (m + 4) * 2048 + fx0);
            aF[m][1] = *(const bf16x8*)(curA + arowB + (m + 4) * 2048 + fx1);
        }
        asm volatile("s_waitcnt lgkmcnt(0)" ::: "memory");
        __builtin_amdgcn_sched_barrier(0);
        __builtin_amdgcn_s_setprio(1);
#pragma unroll
        for (int m = 0; m < 4; ++m)
#pragma unroll
            for (int n = 0; n < 4; ++n) {
                MFMA_(aF[m][0], bF[n][0], m + 4, n);
                MFMA_(aF[m][1], bF[n][1], m + 4, n);
            }
        __builtin_amdgcn_s_setprio(0);

        // ---- iter end: certify stage(kt+1) complete, then ONE barrier ----
        asm volatile("s_waitcnt vmcnt(0)" ::: "memory");
        __builtin_amdgcn_s_barrier();
        asm volatile("" ::: "memory");
    }

    // ---- epilogue: C/D frag layout col = lane&15, row = (lane>>4)*4 + q.
    const int rbase = i0 + wm * 128 + lq * 4;
    const int cbase = j0 + wn * 64 + lr;
    float* red = (float*)smem;    // [256 rows][66] floats
#pragma unroll
    for (int m = 0; m < 8; ++m) {
#pragma unroll
        for (int q = 0; q < 4; ++q) {
            const int row = rbase + m * 16 + q;
            float rs = 0.0f;
#pragma unroll
            for (int n = 0; n < 4; ++n) {
                const int col = cbase + n * 16;
                short o = 0;
                if (row < NN && col < NN) {
                    float x = acc[m][n][q] + b2[col] + bf2f(adjw[(size_t)row * NN + col]);
                    x = fmaxf(x, 0.0f);
                    if (row == col) x += 1.0f;
                    o = f2bf(x);
                    rs += x;
                }
                m_bf[((size_t)b * P + row) * P + col] = o;
            }
            red[(wm * 128 + m * 16 + lq * 4 + q) * 66 + (wn * 16 + lr)] = rs;
        }
    }
    __syncthreads();
    if (t < 256) {
        const float* rr = red + t * 66;
        float s = 0.0f;
#pragma unroll
        for (int k2 = 0; k2 < 64; ++k2) s += rr[k2];
        const int row = i0 + t;
        if (row < NN)
            rowpart[((size_t)b * 8 + (tile >> 3)) * 2048 + row] = s;
    }
#undef MFMA_
#undef STAGE_ALL
}

// ---------------------------------------------------------------------------
// m97-style 128x128 MFMA GEMM (GEMM0 and the K-split aggregations)
// EPI 0: adjW3bf = bf16(acc + b3[col])
// EPI 2: part[kt][b][row][col<OUTD] = bf16(acc), K range [kt*512, +512)
// ---------------------------------------------------------------------------
template<int EPI, int OUTD>
__global__ __launch_bounds__(256) void k_mfma(
    const short* __restrict__ Abase, const short* __restrict__ Bbase,
    const float* __restrict__ bias, const short* __restrict__ adjw,
    void* __restrict__ Cout, short* __restrict__ part, size_t aBatch)
{
    __shared__ short shA[4096];
    __shared__ short shB[4096];
    const int t = threadIdx.x;
    const int w = t >> 6, lane = t & 63;
    const int wr = w >> 1, wc = w & 1;

    int i0, j0, b, kt = 0;
    if (EPI == 2) {
        i0 = blockIdx.x * 128; j0 = 0; kt = blockIdx.y; b = blockIdx.z;
    } else {
        i0 = blockIdx.x * 128; j0 = blockIdx.y * 128; b = 0;
    }
    const int kb = (EPI == 2) ? kt * (P / 4) : 0;
    const int ke = (EPI == 2) ? kt * (P / 4) + (P / 4) : P;

    const short* A  = Abase + (size_t)b * aBatch;
    const short* Bm = Bbase + ((EPI == 2) ? (size_t)b * 128 * P : (size_t)0);

    f32x4 acc[4][4];
#pragma unroll
    for (int m = 0; m < 4; ++m)
#pragma unroll
        for (int n = 0; n < 4; ++n) acc[m][n] = (f32x4){0.f, 0.f, 0.f, 0.f};

    const int lidx0 = w * 128 + lane;
    const int lidx1 = lidx0 + 64;
    const short* aS0 = A  + (size_t)(i0 + (lidx0 >> 2)) * P + (lidx0 & 3) * 8;
    const short* aS1 = A  + (size_t)(i0 + (lidx1 >> 2)) * P + (lidx1 & 3) * 8;
    const short* bS0 = Bm + (size_t)(j0 + (lidx0 >> 2)) * P + (lidx0 & 3) * 8;
    const short* bS1 = Bm + (size_t)(j0 + (lidx1 >> 2)) * P + (lidx1 & 3) * 8;
    short* ldA0 = shA + (w * 128) * 8;
    short* ldA1 = shA + (w * 128 + 64) * 8;
    short* ldB0 = shB + (w * 128) * 8;
    short* ldB1 = shB + (w * 128 + 64) * 8;

    const int lr = lane & 15, lq = lane >> 4;
    const int aoff = (wr * 64 + lr) * 32 + lq * 8;
    const int boff = (wc * 64 + lr) * 32 + lq * 8;

    for (int k0 = kb; k0 < ke; k0 += 32) {
        gl2lds16(aS0 + k0, ldA0);
        gl2lds16(aS1 + k0, ldA1);
        gl2lds16(bS0 + k0, ldB0);
        gl2lds16(bS1 + k0, ldB1);
        __syncthreads();
        bf16x8 aF[4], bF[4];
#pragma unroll
        for (int m = 0; m < 4; ++m) aF[m] = *(const bf16x8*)(shA + aoff + m * 512);
#pragma unroll
        for (int n = 0; n < 4; ++n) bF[n] = *(const bf16x8*)(shB + boff + n * 512);
#pragma unroll
        for (int m = 0; m < 4; ++m)
#pragma unroll
            for (int n = 0; n < 4; ++n)
                acc[m][n] = __builtin_amdgcn_mfma_f32_16x16x32_bf16(aF[m], bF[n], acc[m][n], 0, 0, 0);
        __syncthreads();
    }

    const int rbase = i0 + wr * 64 + lq * 4;
    const int cbase = j0 + wc * 64 + lr;
#pragma unroll
    for (int m = 0; m < 4; ++m) {
#pragma unroll
        for (int n = 0; n < 4; ++n) {
            const int col = cbase + n * 16;
#pragma unroll
            for (int q = 0; q < 4; ++q) {
                const int row = rbase + m * 16 + q;
                float v = acc[m][n][q];
                if (EPI == 0) {
                    if (row < NN && col < NN)
                        ((short*)Cout)[(size_t)row * NN + col] = f2bf(v + bias[col]);
                } else {
                    if (row < NN && col < OUTD)
                        part[((size_t)(kt * BB + b) * NN + row) * OUTD + col] = f2bf(v);
                }
            }
        }
    }
}

// ---------------------------------------------------------------------------
// k_combred: fused {combine 4 bf16 partials + bias + dinv scale -> conc}
// AND per-(b,c) mean/max reduction (c = flat-chunk channel view).
// ---------------------------------------------------------------------------
__global__ __launch_bounds__(256) void k_combred(
    const short* __restrict__ part, const float* __restrict__ dinv,
    const float* __restrict__ bias, float* __restrict__ conc,
    float* __restrict__ avg, float* __restrict__ mx)
{
    const int c = blockIdx.x, b = blockIdx.y, t = threadIdx.x;
    const size_t S = (size_t)BB * NN * 128;
    const size_t base = (size_t)b * NN * 128;
    float sm = 0.0f, sx = -3.402823466e+38f;
    for (int n = t; n < NN; n += 256) {
        const size_t f = (size_t)c * NN + n;
        const int i = (int)(f >> 7), o = (int)(f & 127);
        const size_t pidx = base + f;
        float s = (bf2f(part[pidx]) + bf2f(part[pidx + S])) +
                  (bf2f(part[pidx + 2 * S]) + bf2f(part[pidx + 3 * S]));
        float v = s * dinv[b * NN + i] + bias[o];
        conc[pidx] = v;
        sm += v; sx = fmaxf(sx, v);
    }
#pragma unroll
    for (int off = 32; off > 0; off >>= 1) {
        sm += __shfl_down(sm, off);
        sx = fmaxf(sx, __shfl_down(sx, off));
    }
    __shared__ float rs[4], rm[4];
    if ((t & 63) == 0) { rs[t >> 6] = sm; rm[t >> 6] = sx; }
    __syncthreads();
    if (t == 0) {
        avg[b * 128 + c] = (rs[0] + rs[1] + rs[2] + rs[3]) * (1.0f / NN);
        mx[b * 128 + c]  = fmaxf(fmaxf(rm[0], rm[1]), fmaxf(rm[2], rm[3]));
    }
}

// fused: combine 4 bf16 partials (OUTD=64) + tanh + GRU output
__global__ __launch_bounds__(256) void k_cfin(
    const short* __restrict__ part, const float* __restrict__ dinv,
    const float* __restrict__ bias, const float* __restrict__ u,
    const float* __restrict__ hidden, float* __restrict__ out)
{
    const size_t idx = (size_t)blockIdx.x * 256 + threadIdx.x;
    const size_t S = (size_t)BB * NN * 64;
    if (idx >= S) return;
    const int o = (int)(idx & 63);
    const size_t r = idx >> 6;
    const int i = (int)(r % NN);
    const int b = (int)(r / NN);
    float s = (bf2f(part[idx]) + bf2f(part[idx + S])) +
              (bf2f(part[idx + 2 * S]) + bf2f(part[idx + 3 * S]));
    float c = tanhf(s * dinv[b * NN + i] + bias[o]);
    float uu = u[idx];
    out[idx] = uu * hidden[idx] + (1.0f - uu) * c;
}

// ---------------------------------------------------------------------------
// zT[b][o][j] = bf16( dinv[b,j] * sum_c x[b,j,c]*W[o,c] ).
// OUT==128 additionally COMPUTES dinv from rowpart and writes it.
// ---------------------------------------------------------------------------
template<int OUT>
__global__ __launch_bounds__(128) void k_xwT(
    const float* __restrict__ inputs, const float* __restrict__ hsrc,
    const float* __restrict__ W, const float* __restrict__ rowpart,
    float* __restrict__ dinv, short* __restrict__ zT)
{
    const int b = blockIdx.y;
    const int j0 = blockIdx.x * 16;
    const int t = threadIdx.x;
    __shared__ float wl[128 * 65];
    __shared__ float xs[16 * 66];
    __shared__ float dj[16];
    for (int idx = t; idx < OUT * 65; idx += 128) wl[idx] = W[idx];
    for (int idx = t; idx < 16 * 64; idx += 128) {
        int jj = idx >> 6, hh = idx & 63, j = j0 + jj;
        xs[jj * 66 + 1 + hh] = (j < NN) ? hsrc[((size_t)b * NN + j) * 64 + hh] : 0.0f;
    }
    if (t < 16) {
        int j = j0 + t;
        xs[t * 66] = (j < NN) ? inputs[(size_t)b * 3 * NN + j] : 0.0f;
        float dv = 0.0f;
        if (j < NN) {
            if (OUT == 128) {
                float s = 0.0f;
#pragma unroll
                for (int jt = 0; jt < 8; ++jt)
                    s += rowpart[((size_t)b * 8 + jt) * 2048 + j];
                dv = rsqrtf(s);
                dinv[b * NN + j] = dv;
            } else {
                dv = dinv[b * NN + j];
            }
        }
        dj[t] = dv;
    }
    __syncthreads();
    for (int jj = 0; jj < 16; ++jj) {
        float a = 0.0f;
        if (t < OUT) {
            const float* xr = &xs[jj * 66];
            const float* wr = &wl[t * 65];
#pragma unroll
            for (int c = 0; c < 65; ++c) a = fmaf(xr[c], wr[c], a);
        }
        int j = j0 + jj;
        zT[((size_t)b * 128 + t) * P + j] = (t < OUT && j < NN) ? f2bf(a * dj[jj]) : (short)0;
    }
}

// ---------------------------------------------------------------------------
// k_satgate: inline channel-attention (CBAM MLP from avg/mx) + spatial
// attention (halo recompute) + GRU gates.
// ---------------------------------------------------------------------------
__global__ __launch_bounds__(256) void k_satgate(
    const float* __restrict__ conc, const float* __restrict__ avg,
    const float* __restrict__ mxv, const float* __restrict__ Wca1,
    const float* __restrict__ Wca2, const float* __restrict__ Wsa,
    const float* __restrict__ hidden, float* __restrict__ rh, float* __restrict__ u)
{
    const int b = blockIdx.y;
    const int n0 = blockIdx.x * 256;
    const int t = threadIdx.x;
    __shared__ float av[128], mv[128], h[16], cas[128];
    __shared__ float wsa[14];
    __shared__ float s0l[262], s1l[262];
    if (t < 128) { av[t] = avg[b * 128 + t]; mv[t] = mxv[b * 128 + t]; }
    if (t >= 128 && t < 142) wsa[t - 128] = Wsa[t - 128];
    __syncthreads();
    if (t < 16) {
        int o8 = t & 7;
        const float* src = (t < 8) ? av : mv;
        float s = 0.0f;
        for (int c = 0; c < 128; ++c) s = fmaf(Wca1[o8 * 128 + c], src[c], s);
        h[t] = fmaxf(s, 0.0f);
    }
    __syncthreads();
    if (t < 128) {
        float s = 0.0f;
#pragma unroll
        for (int k = 0; k < 8; ++k) s = fmaf(Wca2[t * 8 + k], h[k] + h[8 + k], s);
        cas[t] = sigf(s);
    }
    __syncthreads();

    const float* cb = conc + (size_t)b * NN * 128;
    {
        const int n = n0 + t;
        float sm = 0.0f, sx = -3.402823466e+38f;
        if (n < NN) {
            for (int c = 0; c < 128; ++c) {
                float v = cas[c] * cb[(size_t)c * NN + n];
                sm += v; sx = fmaxf(sx, v);
            }
            s0l[t + 3] = sm * (1.0f / 128.0f);
            s1l[t + 3] = sx;
        } else { s0l[t + 3] = 0.0f; s1l[t + 3] = 0.0f; }
    }
    if (t < 6) {
        const int hn = (t < 3) ? (n0 - 3 + t) : (n0 + 256 + (t - 3));
        const int hi = (t < 3) ? t : (256 + t);
        float sm = 0.0f, sx = -3.402823466e+38f;
        if (hn >= 0 && hn < NN) {
            for (int c = 0; c < 128; ++c) {
                float v = cas[c] * cb[(size_t)c * NN + hn];
                sm += v; sx = fmaxf(sx, v);
            }
            s0l[hi] = sm * (1.0f / 128.0f);
            s1l[hi] = sx;
        } else { s0l[hi] = 0.0f; s1l[hi] = 0.0f; }
    }
    __syncthreads();

    const int n = n0 + t;
    if (n >= NN) return;
    float sa = 0.0f;
#pragma unroll
    for (int k = 0; k < 7; ++k)
        sa += wsa[k] * s0l[t + k] + wsa[7 + k] * s1l[t + k];
    float gs = sigf(sa);
    for (int c = 0; c < 128; ++c) {
        float v = gs * cas[c] * cb[(size_t)c * NN + n];
        float g = sigf(v);
        if (c < 64)
            rh[(size_t)b * NN * 64 + (size_t)c * NN + n] =
                g * hidden[(size_t)b * NN * 64 + (size_t)c * NN + n];
        else
            u[(size_t)b * NN * 64 + (size_t)(c - 64) * NN + n] = g;
    }
}

extern "C" void kernel_launch(void* const* d_in, const int* in_sizes, int n_in,
                              void* d_out, int out_size, void* d_ws, size_t ws_size,
                              hipStream_t stream)
{
    (void)in_sizes; (void)n_in; (void)out_size; (void)ws_size;
    const float* inputs = (const float*)d_in[0];
    const float* hidden = (const float*)d_in[1];
    const float* adj    = (const float*)d_in[2];
    const float* windd  = (const float*)d_in[3];
    const float* W2     = (const float*)d_in[4];
    const float* b2     = (const float*)d_in[5];
    const float* W3     = (const float*)d_in[6];
    const float* b3     = (const float*)d_in[7];
    const float* W1a    = (const float*)d_in[8];
    const float* b1a    = (const float*)d_in[9];
    const float* W1b    = (const float*)d_in[10];
    const float* b1b    = (const float*)d_in[11];
    const float* Wca1   = (const float*)d_in[12];
    const float* Wca2   = (const float*)d_in[13];
    const float* Wsa    = (const float*)d_in[14];
    float* out = (float*)d_out;

    // ---- workspace layout (byte offsets; unions by lifetime) ----
    char* W = (char*)d_ws;
    short* adjW3bf = (short*)(W + 0);
    short* W2bf    = (short*)(W + 8000000);
    short* W3bf    = (short*)(W + 16388608);
    short* adjbf   = (short*)(W + 24777216);
    short* m_bf    = (short*)(W + 16388608);     // union with {W3bf, adjbf}
    char* D = W + 83497472;
    short* d1bf = (short*)D;                     // union with post-GEMM1 buffers
    float* dinv = (float*)(D + 0);
    float* avgb = (float*)(D + 64000);
    float* mxb  = (float*)(D + 68096);
    short* zT   = (short*)(D + 204800);
    float* conc = (float*)(D + 4399104);
    float* rh   = (float*)(D + 12591104);
    float* ubuf = (float*)(D + 16687104);
    short* part = (short*)(D + 24879104);
    float* rowpart = (float*)(D + 67108864);     // AFTER d1bf (live during k_gd)

    const size_t PP = (size_t)P * P;

    k_cvt<<<dim3(P, 4), 256, 0, stream>>>(W2, W3, adj, windd, inputs,
                                          W2bf, W3bf, adjbf, d1bf);
    k_mfma<0, 0><<<dim3(16, 16, 1), 256, 0, stream>>>(adjbf, W3bf, b3, nullptr, adjW3bf, nullptr, 0);
    k_gd<<<dim3(64, BB), 512, 0, stream>>>(d1bf, W2bf, b2, adjW3bf, m_bf, rowpart);
    k_xwT<128><<<dim3(128, BB), 128, 0, stream>>>(inputs, hidden, W1a, rowpart, dinv, zT);
    k_mfma<2, 128><<<dim3(16, 4, BB), 256, 0, stream>>>(m_bf, zT, nullptr, nullptr, nullptr, part, PP);
    k_combred<<<dim3(128, BB), 256, 0, stream>>>(part, dinv, b1a, conc, avgb, mxb);
    k_satgate<<<dim3(8, BB), 256, 0, stream>>>(conc, avgb, mxb, Wca1, Wca2, Wsa, hidden, rh, ubuf);
    k_xwT<64><<<dim3(128, BB), 128, 0, stream>>>(inputs, rh, W1b, rowpart, dinv, zT);
    k_mfma<2, 64><<<dim3(16, 4, BB), 256, 0, stream>>>(m_bf, zT, nullptr, nullptr, nullptr, part, PP);
    k_cfin<<<(BB * NN * 64 + 255) / 256, 256, 0, stream>>>(part, dinv, b1b, ubuf, hidden, out);
}

// Round 14
// 387.958 us; speedup vs baseline: 1.0220x; 1.0220x over previous
//
#include <hip/hip_runtime.h>

#define NN 2000
#define BB 8
#define P  2048   // padded dim for all MFMA operands
#define NIT 32    // K iterations of 64 for k_gd

typedef __attribute__((ext_vector_type(8))) short bf16x8;
typedef __attribute__((ext_vector_type(4))) float f32x4;

__device__ __forceinline__ float sigf(float x) { return 1.0f / (1.0f + expf(-x)); }

__device__ __forceinline__ short f2bf(float x) {
    union { float f; unsigned u; } v; v.f = x;
    unsigned r = v.u + 0x7fffu + ((v.u >> 16) & 1u);   // round-nearest-even
    return (short)(r >> 16);
}
__device__ __forceinline__ float bf2f(short h) {
    union { unsigned u; float f; } v; v.u = ((unsigned)(unsigned short)h) << 16; return v.f;
}

__device__ __forceinline__ void gl2lds16(const short* g, short* l) {
    __builtin_amdgcn_global_load_lds(
        (const __attribute__((address_space(1))) void*)g,
        (__attribute__((address_space(3))) void*)l, 16, 0, 0);
}

// ---------------------------------------------------------------------------
// k_cvt: merged weight conversion + dynamic-adjacency build.
// ---------------------------------------------------------------------------
__global__ __launch_bounds__(256) void k_cvt(
    const float* __restrict__ W2, const float* __restrict__ W3,
    const float* __restrict__ adj, const float* __restrict__ windd,
    const float* __restrict__ inputs,
    short* __restrict__ W2bf, short* __restrict__ W3bf,
    short* __restrict__ adjbf, short* __restrict__ d1bf)
{
    const int i = blockIdx.x, sel = blockIdx.y, t = threadIdx.x;
    const bool live = (i < NN) && (t < 250);
    if (sel < 3) {
        const float* s = (sel == 0) ? W2 : (sel == 1) ? W3 : adj;
        short* d = ((sel == 0) ? W2bf : (sel == 1) ? W3bf : adjbf) + ((size_t)i) * P + t * 8;
        bf16x8 v;
#pragma unroll
        for (int e = 0; e < 8; ++e) v[e] = 0;
        if (live) {
            const float* p = s + (size_t)i * NN + t * 8;
            float4 x0 = *(const float4*)p;
            float4 x1 = *(const float4*)(p + 4);
            float a[8] = {x0.x,x0.y,x0.z,x0.w,x1.x,x1.y,x1.z,x1.w};
#pragma unroll
            for (int e = 0; e < 8; ++e) v[e] = f2bf(a[e]);
        }
        *(bf16x8*)d = v;
    } else {
        const float DEG = 0.01745329251994329577f;
        float cw[8], sw[8];
        if (live) {
            const float* p = windd + (size_t)i * NN + t * 8;
            float4 x0 = *(const float4*)p;
            float4 x1 = *(const float4*)(p + 4);
            float a[8] = {x0.x,x0.y,x0.z,x0.w,x1.x,x1.y,x1.z,x1.w};
#pragma unroll
            for (int e = 0; e < 8; ++e) {
                float r = a[e] * DEG;
                cw[e] = __cosf(r);
                sw[e] = __sinf(r);
            }
        }
        __shared__ float cwn[8], swn[8];
        if (t < 8 && i < NN) {
            float wn = inputs[(size_t)t * 3 * NN + 2 * NN + i] * (360.0f * DEG);
            cwn[t] = __cosf(wn);
            swn[t] = __sinf(wn);
        }
        __syncthreads();
#pragma unroll
        for (int b = 0; b < BB; ++b) {
            bf16x8 v;
#pragma unroll
            for (int e = 0; e < 8; ++e) v[e] = 0;
            if (live) {
                const float cb_ = cwn[b], sb_ = swn[b];
#pragma unroll
                for (int e = 0; e < 8; ++e)
                    v[e] = f2bf(fmaxf(fmaf(cw[e], cb_, sw[e] * sb_), 0.0f));
            }
            *(bf16x8*)(d1bf + ((size_t)b * P + i) * P + t * 8) = v;
        }
    }
}

// ---------------------------------------------------------------------------
// k_gd: wind GEMM (FROZEN R11 structure).
// ---------------------------------------------------------------------------
__global__ __launch_bounds__(512, 2) void k_gd(
    const short* __restrict__ d1bf, const short* __restrict__ W2bf,
    const float* __restrict__ b2, const short* __restrict__ adjw,
    short* __restrict__ m_bf, float* __restrict__ rowpart)
{
    __shared__ char smem[131072];   // A slots: [2][256][128B] at 0; B slots at +65536
    const int t = threadIdx.x;
    const int w = t >> 6, lane = t & 63;
    const int wm = w >> 2, wn = w & 3;
    const int lr = lane & 15, lq = lane >> 4;
    const int tile = blockIdx.x;               // 0..63
    const int b = blockIdx.y;
    const int i0 = (tile & 7) * 256;           // same-XCD blocks share A-panel
    const int j0 = (tile >> 3) * 256;
    const short* A  = d1bf + (size_t)b * P * P;
    const short* Bm = W2bf;

    const short* srcA[4];
    const short* srcB[4];
#pragma unroll
    for (int q = 0; q < 4; ++q) {
        const int c = q * 512 + t;
        const int r = c >> 3;
        const int g = (c & 7) ^ (r & 7);
        srcA[q] = A  + (size_t)(i0 + r) * P + g * 8;
        srcB[q] = Bm + (size_t)(j0 + r) * P + g * 8;
    }

#define STAGE_ALL(slot, ktI) do {                                                      \
        gl2lds16(srcA[0] + (ktI) * 64, (short*)(smem + (slot) * 32768 + (w * 64) * 16));          \
        gl2lds16(srcA[1] + (ktI) * 64, (short*)(smem + (slot) * 32768 + (512 + w * 64) * 16));    \
        gl2lds16(srcA[2] + (ktI) * 64, (short*)(smem + (slot) * 32768 + (1024 + w * 64) * 16));   \
        gl2lds16(srcA[3] + (ktI) * 64, (short*)(smem + (slot) * 32768 + (1536 + w * 64) * 16));   \
        gl2lds16(srcB[0] + (ktI) * 64, (short*)(smem + 65536 + (slot) * 32768 + (w * 64) * 16));          \
        gl2lds16(srcB[1] + (ktI) * 64, (short*)(smem + 65536 + (slot) * 32768 + (512 + w * 64) * 16));    \
        gl2lds16(srcB[2] + (ktI) * 64, (short*)(smem + 65536 + (slot) * 32768 + (1024 + w * 64) * 16));   \
        gl2lds16(srcB[3] + (ktI) * 64, (short*)(smem + 65536 + (slot) * 32768 + (1536 + w * 64) * 16)); } while (0)

    const int fx0 = (lq << 4) ^ ((lr & 7) << 4);          // ks=0
    const int fx1 = ((4 + lq) << 4) ^ ((lr & 7) << 4);    // ks=1
    const int arowB = (wm * 128 + lr) * 128;              // + m*2048
    const int browB = (wn * 64 + lr) * 128;               // + n*2048

    f32x4 acc[8][4];
#pragma unroll
    for (int m = 0; m < 8; ++m)
#pragma unroll
        for (int n = 0; n < 4; ++n) acc[m][n] = (f32x4){0.f, 0.f, 0.f, 0.f};
    bf16x8 aF[4][2], bF[4][2];

    STAGE_ALL(0, 0);
    asm volatile("s_waitcnt vmcnt(0)" ::: "memory");
    __builtin_amdgcn_s_barrier();
    asm volatile("" ::: "memory");

#define MFMA_(a_, b_, m, n) acc[m][n] = __builtin_amdgcn_mfma_f32_16x16x32_bf16(a_, b_, acc[m][n], 0, 0, 0)

    for (int kt = 0; kt < NIT; ++kt) {
        char* curA = smem + (kt & 1) * 32768;
        char* curB = smem + 65536 + (kt & 1) * 32768;
        const int stgSlot = (kt + 1) & 1;
        const int stgKt = (kt + 1 < NIT) ? (kt + 1) : (NIT - 1);  // clamped: never read

        STAGE_ALL(stgSlot, stgKt);

        // ---- phase A: read A m0-3 + B n0-3; 32 MFMA ----
#pragma unroll
        for (int m = 0; m < 4; ++m) {
            aF[m][0] = *(const bf16x8*)(curA + arowB + m * 2048 + fx0);
            aF[m][1] = *(const bf16x8*)(curA + arowB + m * 2048 + fx1);
        }
#pragma unroll
        for (int n = 0; n < 4; ++n) {
            bF[n][0] = *(const bf16x8*)(curB + browB + n * 2048 + fx0);
            bF[n][1] = *(const bf16x8*)(curB + browB + n * 2048 + fx1);
        }
        asm volatile("s_waitcnt lgkmcnt(0)" ::: "memory");
        __builtin_amdgcn_sched_barrier(0);
        __builtin_amdgcn_s_setprio(1);
#pragma unroll
        for (int m = 0; m < 4; ++m)
#pragma unroll
            for (int n = 0; n < 4; ++n) {
                MFMA_(aF[m][0], bF[n][0], m, n);
                MFMA_(aF[m][1], bF[n][1], m, n);
            }
        __builtin_amdgcn_s_setprio(0);

        // ---- phase B: read A m4-7; 32 MFMA ----
#pragma unroll
        for (int m = 0; m < 4; ++m) {
            aF[m][0] = *(const bf16x8*)(curA + arowB + (m + 4) * 2048 + fx0);
            aF[m][1] = *(const bf16x8*)(curA + arowB + (m + 4) * 2048 + fx1);
        }
        asm volatile("s_waitcnt lgkmcnt(0)" ::: "memory");
        __builtin_amdgcn_sched_barrier(0);
        __builtin_amdgcn_s_setprio(1);
#pragma unroll
        for (int m = 0; m < 4; ++m)
#pragma unroll
            for (int n = 0; n < 4; ++n) {
                MFMA_(aF[m][0], bF[n][0], m + 4, n);
                MFMA_(aF[m][1], bF[n][1], m + 4, n);
            }
        __builtin_amdgcn_s_setprio(0);

        asm volatile("s_waitcnt vmcnt(0)" ::: "memory");
        __builtin_amdgcn_s_barrier();
        asm volatile("" ::: "memory");
    }

    const int rbase = i0 + wm * 128 + lq * 4;
    const int cbase = j0 + wn * 64 + lr;
    float* red = (float*)smem;    // [256 rows][66] floats
#pragma unroll
    for (int m = 0; m < 8; ++m) {
#pragma unroll
        for (int q = 0; q < 4; ++q) {
            const int row = rbase + m * 16 + q;
            float rs = 0.0f;
#pragma unroll
            for (int n = 0; n < 4; ++n) {
                const int col = cbase + n * 16;
                short o = 0;
                if (row < NN && col < NN) {
                    float x = acc[m][n][q] + b2[col] + bf2f(adjw[(size_t)row * NN + col]);
                    x = fmaxf(x, 0.0f);
                    if (row == col) x += 1.0f;
                    o = f2bf(x);
                    rs += x;
                }
                m_bf[((size_t)b * P + row) * P + col] = o;
            }
            red[(wm * 128 + m * 16 + lq * 4 + q) * 66 + (wn * 16 + lr)] = rs;
        }
    }
    __syncthreads();
    if (t < 256) {
        const float* rr = red + t * 66;
        float s = 0.0f;
#pragma unroll
        for (int k2 = 0; k2 < 64; ++k2) s += rr[k2];
        const int row = i0 + t;
        if (row < NN)
            rowpart[((size_t)b * 8 + (tile >> 3)) * 2048 + row] = s;
    }
#undef MFMA_
#undef STAGE_ALL
}

// ---------------------------------------------------------------------------
// m97-style 128x128 MFMA GEMM with the R10-proven conflict-free 64B-row
// swizzle: source granule g = p ^ ((r>>1)&3); read XOR lq ^ ((lr>>1)&3).
// EPI 0: adjW3bf = bf16(acc + b3[col])
// EPI 2: part[kt][b][row][col<128] = bf16(acc), K range [kt*512, +512)
// ---------------------------------------------------------------------------
template<int EPI>
__global__ __launch_bounds__(256) void k_mfma(
    const short* __restrict__ Abase, const short* __restrict__ Bbase,
    const float* __restrict__ bias,
    void* __restrict__ Cout, short* __restrict__ part, size_t aBatch)
{
    __shared__ short shA[4096];
    __shared__ short shB[4096];
    const int t = threadIdx.x;
    const int w = t >> 6, lane = t & 63;
    const int wr = w >> 1, wc = w & 1;

    int i0, j0, b, kt = 0;
    if (EPI == 2) {
        i0 = blockIdx.x * 128; j0 = 0; kt = blockIdx.y; b = blockIdx.z;
    } else {
        i0 = blockIdx.x * 128; j0 = blockIdx.y * 128; b = 0;
    }
    const int kb = (EPI == 2) ? kt * (P / 4) : 0;
    const int ke = (EPI == 2) ? kt * (P / 4) + (P / 4) : P;

    const short* A  = Abase + (size_t)b * aBatch;
    const short* Bm = Bbase + ((EPI == 2) ? (size_t)b * 128 * P : (size_t)0);

    f32x4 acc[4][4];
#pragma unroll
    for (int m = 0; m < 4; ++m)
#pragma unroll
        for (int n = 0; n < 4; ++n) acc[m][n] = (f32x4){0.f, 0.f, 0.f, 0.f};

    const int lidx0 = w * 128 + lane;
    const int lidx1 = lidx0 + 64;
    const int rA0 = lidx0 >> 2, rA1 = lidx1 >> 2;
    const int gA0 = (lidx0 & 3) ^ ((lidx0 >> 3) & 3);
    const int gA1 = (lidx1 & 3) ^ ((lidx1 >> 3) & 3);
    const short* aS0 = A  + (size_t)(i0 + rA0) * P + gA0 * 8;
    const short* aS1 = A  + (size_t)(i0 + rA1) * P + gA1 * 8;
    const short* bS0 = Bm + (size_t)(j0 + rA0) * P + gA0 * 8;
    const short* bS1 = Bm + (size_t)(j0 + rA1) * P + gA1 * 8;
    short* ldA0 = shA + lidx0 * 8 - lane * 8 + lane * 8;   // = shA + lidx0*8
    short* ldA1 = shA + lidx1 * 8;
    short* ldB0 = shB + lidx0 * 8;
    short* ldB1 = shB + lidx1 * 8;

    const int lr = lane & 15, lq = lane >> 4;
    const int axr = (lq ^ ((lr >> 1) & 3)) << 3;
    const int aoff = (wr * 64 + lr) * 32 + axr;
    const int boff = (wc * 64 + lr) * 32 + axr;

    for (int k0 = kb; k0 < ke; k0 += 32) {
        gl2lds16(aS0 + k0, ldA0);
        gl2lds16(aS1 + k0, ldA1);
        gl2lds16(bS0 + k0, ldB0);
        gl2lds16(bS1 + k0, ldB1);
        __syncthreads();
        bf16x8 aF[4], bF[4];
#pragma unroll
        for (int m = 0; m < 4; ++m) aF[m] = *(const bf16x8*)(shA + aoff + m * 512);
#pragma unroll
        for (int n = 0; n < 4; ++n) bF[n] = *(const bf16x8*)(shB + boff + n * 512);
#pragma unroll
        for (int m = 0; m < 4; ++m)
#pragma unroll
            for (int n = 0; n < 4; ++n)
                acc[m][n] = __builtin_amdgcn_mfma_f32_16x16x32_bf16(aF[m], bF[n], acc[m][n], 0, 0, 0);
        __syncthreads();
    }

    const int rbase = i0 + wr * 64 + lq * 4;
    const int cbase = j0 + wc * 64 + lr;
#pragma unroll
    for (int m = 0; m < 4; ++m) {
#pragma unroll
        for (int n = 0; n < 4; ++n) {
            const int col = cbase + n * 16;
#pragma unroll
            for (int q = 0; q < 4; ++q) {
                const int row = rbase + m * 16 + q;
                float v = acc[m][n][q];
                if (EPI == 0) {
                    if (row < NN && col < NN)
                        ((short*)Cout)[(size_t)row * NN + col] = f2bf(v + bias[col]);
                } else {
                    if (row < NN && col < 128)
                        part[((size_t)(kt * BB + b) * NN + row) * 128 + col] = f2bf(v);
                }
            }
        }
    }
}

// ---------------------------------------------------------------------------
// k_agg64: second aggregation, tile 128(M) x 64(N) (no wasted zero columns),
// 4 waves (2M x 2N, wave tile 64x32), BK=32, K-split grid (16,4,BB),
// conflict-free swizzle as k_mfma. part[kt][b][row][col<64] = bf16(acc).
// ---------------------------------------------------------------------------
__global__ __launch_bounds__(256) void k_agg64(
    const short* __restrict__ m_bf, const short* __restrict__ zT,
    short* __restrict__ part)
{
    __shared__ short shA[4096];   // 128 rows x 32
    __shared__ short shB[2048];   // 64 rows x 32
    const int t = threadIdx.x;
    const int w = t >> 6, lane = t & 63;
    const int wr = w >> 1, wc = w & 1;
    const int i0 = blockIdx.x * 128;
    const int kt = blockIdx.y, b = blockIdx.z;
    const int kb = kt * (P / 4), ke = kb + (P / 4);
    const short* A  = m_bf + (size_t)b * P * P;
    const short* Bm = zT + (size_t)b * 128 * P;

    f32x4 acc[4][2];
#pragma unroll
    for (int m = 0; m < 4; ++m)
#pragma unroll
        for (int n = 0; n < 2; ++n) acc[m][n] = (f32x4){0.f, 0.f, 0.f, 0.f};

    // A: 512 chunks, 2/thread; B: 256 chunks, 1/thread
    const int lidx0 = w * 128 + lane;
    const int lidx1 = lidx0 + 64;
    const int gA0 = (lidx0 & 3) ^ ((lidx0 >> 3) & 3);
    const int gA1 = (lidx1 & 3) ^ ((lidx1 >> 3) & 3);
    const int gB  = (t & 3) ^ ((t >> 3) & 3);
    const short* aS0 = A  + (size_t)(i0 + (lidx0 >> 2)) * P + gA0 * 8;
    const short* aS1 = A  + (size_t)(i0 + (lidx1 >> 2)) * P + gA1 * 8;
    const short* bS  = Bm + (size_t)(t >> 2) * P + gB * 8;
    short* ldA0 = shA + lidx0 * 8;
    short* ldA1 = shA + lidx1 * 8;
    short* ldB  = shB + t * 8;

    const int lr = lane & 15, lq = lane >> 4;
    const int axr = (lq ^ ((lr >> 1) & 3)) << 3;
    const int aoff = (wr * 64 + lr) * 32 + axr;
    const int boff = (wc * 32 + lr) * 32 + axr;

    for (int k0 = kb; k0 < ke; k0 += 32) {
        gl2lds16(aS0 + k0, ldA0);
        gl2lds16(aS1 + k0, ldA1);
        gl2lds16(bS + k0, ldB);
        __syncthreads();
        bf16x8 aF[4], bF[2];
#pragma unroll
        for (int m = 0; m < 4; ++m) aF[m] = *(const bf16x8*)(shA + aoff + m * 512);
#pragma unroll
        for (int n = 0; n < 2; ++n) bF[n] = *(const bf16x8*)(shB + boff + n * 512);
#pragma unroll
        for (int m = 0; m < 4; ++m)
#pragma unroll
            for (int n = 0; n < 2; ++n)
                acc[m][n] = __builtin_amdgcn_mfma_f32_16x16x32_bf16(aF[m], bF[n], acc[m][n], 0, 0, 0);
        __syncthreads();
    }

    const int rbase = i0 + wr * 64 + lq * 4;
    const int cbase = wc * 32 + lr;
#pragma unroll
    for (int m = 0; m < 4; ++m) {
#pragma unroll
        for (int n = 0; n < 2; ++n) {
            const int col = cbase + n * 16;
#pragma unroll
            for (int q = 0; q < 4; ++q) {
                const int row = rbase + m * 16 + q;
                if (row < NN)
                    part[((size_t)(kt * BB + b) * NN + row) * 64 + col] = f2bf(acc[m][n][q]);
            }
        }
    }
}

// ---------------------------------------------------------------------------
// k_combred: fused {combine 4 bf16 partials + bias + dinv scale -> conc}
// AND per-(b,c) mean/max reduction.
// ---------------------------------------------------------------------------
__global__ __launch_bounds__(256) void k_combred(
    const short* __restrict__ part, const float* __restrict__ dinv,
    const float* __restrict__ bias, float* __restrict__ conc,
    float* __restrict__ avg, float* __restrict__ mx)
{
    const int c = blockIdx.x, b = blockIdx.y, t = threadIdx.x;
    const size_t S = (size_t)BB * NN * 128;
    const size_t base = (size_t)b * NN * 128;
    float sm = 0.0f, sx = -3.402823466e+38f;
    for (int n = t; n < NN; n += 256) {
        const size_t f = (size_t)c * NN + n;
        const int i = (int)(f >> 7), o = (int)(f & 127);
        const size_t pidx = base + f;
        float s = (bf2f(part[pidx]) + bf2f(part[pidx + S])) +
                  (bf2f(part[pidx + 2 * S]) + bf2f(part[pidx + 3 * S]));
        float v = s * dinv[b * NN + i] + bias[o];
        conc[pidx] = v;
        sm += v; sx = fmaxf(sx, v);
    }
#pragma unroll
    for (int off = 32; off > 0; off >>= 1) {
        sm += __shfl_down(sm, off);
        sx = fmaxf(sx, __shfl_down(sx, off));
    }
    __shared__ float rs[4], rm[4];
    if ((t & 63) == 0) { rs[t >> 6] = sm; rm[t >> 6] = sx; }
    __syncthreads();
    if (t == 0) {
        avg[b * 128 + c] = (rs[0] + rs[1] + rs[2] + rs[3]) * (1.0f / NN);
        mx[b * 128 + c]  = fmaxf(fmaxf(rm[0], rm[1]), fmaxf(rm[2], rm[3]));
    }
}

// fused: combine 4 bf16 partials (64-wide) + tanh + GRU output
__global__ __launch_bounds__(256) void k_cfin(
    const short* __restrict__ part, const float* __restrict__ dinv,
    const float* __restrict__ bias, const float* __restrict__ u,
    const float* __restrict__ hidden, float* __restrict__ out)
{
    const size_t idx = (size_t)blockIdx.x * 256 + threadIdx.x;
    const size_t S = (size_t)BB * NN * 64;
    if (idx >= S) return;
    const int o = (int)(idx & 63);
    const size_t r = idx >> 6;
    const int i = (int)(r % NN);
    const int b = (int)(r / NN);
    float s = (bf2f(part[idx]) + bf2f(part[idx + S])) +
              (bf2f(part[idx + 2 * S]) + bf2f(part[idx + 3 * S]));
    float c = tanhf(s * dinv[b * NN + i] + bias[o]);
    float uu = u[idx];
    out[idx] = uu * hidden[idx] + (1.0f - uu) * c;
}

// ---------------------------------------------------------------------------
// zT[b][o][j] = bf16( dinv[b,j] * sum_c x[b,j,c]*W[o,c] ).
// OUT==128 additionally COMPUTES dinv from rowpart and writes it.
// ---------------------------------------------------------------------------
template<int OUT>
__global__ __launch_bounds__(128) void k_xwT(
    const float* __restrict__ inputs, const float* __restrict__ hsrc,
    const float* __restrict__ W, const float* __restrict__ rowpart,
    float* __restrict__ dinv, short* __restrict__ zT)
{
    const int b = blockIdx.y;
    const int j0 = blockIdx.x * 16;
    const int t = threadIdx.x;
    __shared__ float wl[128 * 65];
    __shared__ float xs[16 * 66];
    __shared__ float dj[16];
    for (int idx = t; idx < OUT * 65; idx += 128) wl[idx] = W[idx];
    for (int idx = t; idx < 16 * 64; idx += 128) {
        int jj = idx >> 6, hh = idx & 63, j = j0 + jj;
        xs[jj * 66 + 1 + hh] = (j < NN) ? hsrc[((size_t)b * NN + j) * 64 + hh] : 0.0f;
    }
    if (t < 16) {
        int j = j0 + t;
        xs[t * 66] = (j < NN) ? inputs[(size_t)b * 3 * NN + j] : 0.0f;
        float dv = 0.0f;
        if (j < NN) {
            if (OUT == 128) {
                float s = 0.0f;
#pragma unroll
                for (int jt = 0; jt < 8; ++jt)
                    s += rowpart[((size_t)b * 8 + jt) * 2048 + j];
                dv = rsqrtf(s);
                dinv[b * NN + j] = dv;
            } else {
                dv = dinv[b * NN + j];
            }
        }
        dj[t] = dv;
    }
    __syncthreads();
    for (int jj = 0; jj < 16; ++jj) {
        float a = 0.0f;
        if (t < OUT) {
            const float* xr = &xs[jj * 66];
            const float* wr = &wl[t * 65];
#pragma unroll
            for (int c = 0; c < 65; ++c) a = fmaf(xr[c], wr[c], a);
        }
        int j = j0 + jj;
        zT[((size_t)b * 128 + t) * P + j] = (t < OUT && j < NN) ? f2bf(a * dj[jj]) : (short)0;
    }
}

// ---------------------------------------------------------------------------
// k_satgate: inline channel-attention + spatial attention + GRU gates.
// ---------------------------------------------------------------------------
__global__ __launch_bounds__(256) void k_satgate(
    const float* __restrict__ conc, const float* __restrict__ avg,
    const float* __restrict__ mxv, const float* __restrict__ Wca1,
    const float* __restrict__ Wca2, const float* __restrict__ Wsa,
    const float* __restrict__ hidden, float* __restrict__ rh, float* __restrict__ u)
{
    const int b = blockIdx.y;
    const int n0 = blockIdx.x * 256;
    const int t = threadIdx.x;
    __shared__ float av[128], mv[128], h[16], cas[128];
    __shared__ float wsa[14];
    __shared__ float s0l[262], s1l[262];
    if (t < 128) { av[t] = avg[b * 128 + t]; mv[t] = mxv[b * 128 + t]; }
    if (t >= 128 && t < 142) wsa[t - 128] = Wsa[t - 128];
    __syncthreads();
    if (t < 16) {
        int o8 = t & 7;
        const float* src = (t < 8) ? av : mv;
        float s = 0.0f;
        for (int c = 0; c < 128; ++c) s = fmaf(Wca1[o8 * 128 + c], src[c], s);
        h[t] = fmaxf(s, 0.0f);
    }
    __syncthreads();
    if (t < 128) {
        float s = 0.0f;
#pragma unroll
        for (int k = 0; k < 8; ++k) s = fmaf(Wca2[t * 8 + k], h[k] + h[8 + k], s);
        cas[t] = sigf(s);
    }
    __syncthreads();

    const float* cb = conc + (size_t)b * NN * 128;
    {
        const int n = n0 + t;
        float sm = 0.0f, sx = -3.402823466e+38f;
        if (n < NN) {
            for (int c = 0; c < 128; ++c) {
                float v = cas[c] * cb[(size_t)c * NN + n];
                sm += v; sx = fmaxf(sx, v);
            }
            s0l[t + 3] = sm * (1.0f / 128.0f);
            s1l[t + 3] = sx;
        } else { s0l[t + 3] = 0.0f; s1l[t + 3] = 0.0f; }
    }
    if (t < 6) {
        const int hn = (t < 3) ? (n0 - 3 + t) : (n0 + 256 + (t - 3));
        const int hi = (t < 3) ? t : (256 + t);
        float sm = 0.0f, sx = -3.402823466e+38f;
        if (hn >= 0 && hn < NN) {
            for (int c = 0; c < 128; ++c) {
                float v = cas[c] * cb[(size_t)c * NN + hn];
                sm += v; sx = fmaxf(sx, v);
            }
            s0l[hi] = sm * (1.0f / 128.0f);
            s1l[hi] = sx;
        } else { s0l[hi] = 0.0f; s1l[hi] = 0.0f; }
    }
    __syncthreads();

    const int n = n0 + t;
    if (n >= NN) return;
    float sa = 0.0f;
#pragma unroll
    for (int k = 0; k < 7; ++k)
        sa += wsa[k] * s0l[t + k] + wsa[7 + k] * s1l[t + k];
    float gs = sigf(sa);
    for (int c = 0; c < 128; ++c) {
        float v = gs * cas[c] * cb[(size_t)c * NN + n];
        float g = sigf(v);
        if (c < 64)
            rh[(size_t)b * NN * 64 + (size_t)c * NN + n] =
                g * hidden[(size_t)b * NN * 64 + (size_t)c * NN + n];
        else
            u[(size_t)b * NN * 64 + (size_t)(c - 64) * NN + n] = g;
    }
}

extern "C" void kernel_launch(void* const* d_in, const int* in_sizes, int n_in,
                              void* d_out, int out_size, void* d_ws, size_t ws_size,
                              hipStream_t stream)
{
    (void)in_sizes; (void)n_in; (void)out_size; (void)ws_size;
    const float* inputs = (const float*)d_in[0];
    const float* hidden = (const float*)d_in[1];
    const float* adj    = (const float*)d_in[2];
    const float* windd  = (const float*)d_in[3];
    const float* W2     = (const float*)d_in[4];
    const float* b2     = (const float*)d_in[5];
    const float* W3     = (const float*)d_in[6];
    const float* b3     = (const float*)d_in[7];
    const float* W1a    = (const float*)d_in[8];
    const float* b1a    = (const float*)d_in[9];
    const float* W1b    = (const float*)d_in[10];
    const float* b1b    = (const float*)d_in[11];
    const float* Wca1   = (const float*)d_in[12];
    const float* Wca2   = (const float*)d_in[13];
    const float* Wsa    = (const float*)d_in[14];
    float* out = (float*)d_out;

    // ---- workspace layout (byte offsets; unions by lifetime) ----
    char* W = (char*)d_ws;
    short* adjW3bf = (short*)(W + 0);
    short* W2bf    = (short*)(W + 8000000);
    short* W3bf    = (short*)(W + 16388608);
    short* adjbf   = (short*)(W + 24777216);
    short* m_bf    = (short*)(W + 16388608);     // union with {W3bf, adjbf}
    char* D = W + 83497472;
    short* d1bf = (short*)D;                     // union with post-GEMM1 buffers
    float* dinv = (float*)(D + 0);
    float* avgb = (float*)(D + 64000);
    float* mxb  = (float*)(D + 68096);
    short* zT   = (short*)(D + 204800);
    float* conc = (float*)(D + 4399104);
    float* rh   = (float*)(D + 12591104);
    float* ubuf = (float*)(D + 16687104);
    short* part = (short*)(D + 24879104);
    float* rowpart = (float*)(D + 67108864);     // AFTER d1bf (live during k_gd)

    const size_t PP = (size_t)P * P;

    k_cvt<<<dim3(P, 4), 256, 0, stream>>>(W2, W3, adj, windd, inputs,
                                          W2bf, W3bf, adjbf, d1bf);
    k_mfma<0><<<dim3(16, 16, 1), 256, 0, stream>>>(adjbf, W3bf, b3, adjW3bf, nullptr, 0);
    k_gd<<<dim3(64, BB), 512, 0, stream>>>(d1bf, W2bf, b2, adjW3bf, m_bf, rowpart);
    k_xwT<128><<<dim3(128, BB), 128, 0, stream>>>(inputs, hidden, W1a, rowpart, dinv, zT);
    k_mfma<2><<<dim3(16, 4, BB), 256, 0, stream>>>(m_bf, zT, nullptr, nullptr, part, PP);
    k_combred<<<dim3(128, BB), 256, 0, stream>>>(part, dinv, b1a, conc, avgb, mxb);
    k_satgate<<<dim3(8, BB), 256, 0, stream>>>(conc, avgb, mxb, Wca1, Wca2, Wsa, hidden, rh, ubuf);
    k_xwT<64><<<dim3(128, BB), 128, 0, stream>>>(inputs, rh, W1b, rowpart, dinv, zT);
    k_agg64<<<dim3(16, 4, BB), 256, 0, stream>>>(m_bf, zT, part);
    k_cfin<<<(BB * NN * 64 + 255) / 256, 256, 0, stream>>>(part, dinv, b1b, ubuf, hidden, out);
}